// Round 1
// baseline (394.980 us; speedup 1.0000x reference)
//
#include <hip/hip_runtime.h>
#include <math.h>

#define OUT_F      4096
#define IN_F       4096
#define NUM_CHUNKS 16384
#define CHUNK_SIZE 1024
#define D_ALPHA    64
#define HIDDEN     256
#define TOKENS     256

// Stage 1: H[c][t] = gelu(dot(codebook[c], w1[t]) + b1[t]), exact gelu.
// 8 chunks per block; each thread owns hidden unit t and register-caches
// its w1 row (64 floats = 16 float4) so w1 is read once per block.
__global__ void hidden_kernel(const float* __restrict__ cb,
                              const float* __restrict__ w1,
                              const float* __restrict__ b1,
                              float* __restrict__ H) {
    const int c0 = blockIdx.x * 8;
    const int t  = threadIdx.x;            // 0..255 == hidden unit
    __shared__ float sa[8 * 64];
    sa[t]       = cb[(size_t)c0 * 64 + t];
    sa[t + 256] = cb[(size_t)c0 * 64 + t + 256];
    __syncthreads();

    float4 w[16];
    const float4* w1r = reinterpret_cast<const float4*>(w1 + t * 64);
#pragma unroll
    for (int q = 0; q < 16; ++q) w[q] = w1r[q];
    const float b = b1[t];

#pragma unroll
    for (int c = 0; c < 8; ++c) {
        float acc = b;
        const float4* sav = reinterpret_cast<const float4*>(sa + c * 64);
#pragma unroll
        for (int q = 0; q < 16; ++q) {
            float4 a4 = sav[q];
            acc += a4.x * w[q].x;
            acc += a4.y * w[q].y;
            acc += a4.z * w[q].z;
            acc += a4.w * w[q].w;
        }
        // exact gelu: 0.5*x*(1+erf(x/sqrt(2)))
        float g = 0.5f * acc * (1.0f + erff(acc * 0.70710678118654752f));
        H[(size_t)(c0 + c) * 256 + t] = g;
    }
}

// C[M][N] = A[M][K] @ B[N][K]^T + bias[N]   (all row-major, K-contiguous)
// 64x64 block tile, BK=32, 256 threads, 4x4 micro-tile per thread.
// LDS stored k-major with +4 pad so float4 reads are 16B-aligned.
__global__ void gemm_abt(const float* __restrict__ A,
                         const float* __restrict__ B,
                         const float* __restrict__ bias,
                         float* __restrict__ C,
                         int M, int N, int K) {
    constexpr int BM = 64, BN = 64, BK = 32;
    __shared__ float As[BK][BM + 4];
    __shared__ float Bs[BK][BN + 4];

    const int m0  = blockIdx.y * BM;
    const int n0  = blockIdx.x * BN;
    const int tid = threadIdx.x;
    const int tx  = tid & 15;   // column group (4 cols)
    const int ty  = tid >> 4;   // row group (4 rows)

    float acc[4][4] = {};

    const int kk_l = tid & 31;        // k within tile
    const int r_l  = (tid >> 5) * 8;  // base row (8 rows per thread)

    for (int k0 = 0; k0 < K; k0 += BK) {
#pragma unroll
        for (int r2 = 0; r2 < 8; ++r2) {
            const int row = r_l + r2;
            As[kk_l][row] = A[(size_t)(m0 + row) * K + k0 + kk_l];
            Bs[kk_l][row] = B[(size_t)(n0 + row) * K + k0 + kk_l];
        }
        __syncthreads();
#pragma unroll
        for (int kk = 0; kk < BK; ++kk) {
            float4 av = *reinterpret_cast<const float4*>(&As[kk][ty * 4]);
            float4 bv = *reinterpret_cast<const float4*>(&Bs[kk][tx * 4]);
            float a[4]  = {av.x, av.y, av.z, av.w};
            float bb[4] = {bv.x, bv.y, bv.z, bv.w};
#pragma unroll
            for (int i = 0; i < 4; ++i)
#pragma unroll
                for (int j = 0; j < 4; ++j)
                    acc[i][j] += a[i] * bb[j];
        }
        __syncthreads();
    }

    const int nb = n0 + tx * 4;
    float4 bias4;
    bias4.x = bias[nb + 0];
    bias4.y = bias[nb + 1];
    bias4.z = bias[nb + 2];
    bias4.w = bias[nb + 3];
#pragma unroll
    for (int i = 0; i < 4; ++i) {
        const int m = m0 + ty * 4 + i;
        float4 o;
        o.x = acc[i][0] + bias4.x;
        o.y = acc[i][1] + bias4.y;
        o.z = acc[i][2] + bias4.z;
        o.w = acc[i][3] + bias4.w;
        *reinterpret_cast<float4*>(&C[(size_t)m * N + nb]) = o;
    }
}

extern "C" void kernel_launch(void* const* d_in, const int* in_sizes, int n_in,
                              void* d_out, int out_size, void* d_ws, size_t ws_size,
                              hipStream_t stream) {
    const float* x        = (const float*)d_in[0];
    const float* codebook = (const float*)d_in[1];
    const float* w1       = (const float*)d_in[2];
    const float* b1       = (const float*)d_in[3];
    const float* w2       = (const float*)d_in[4];
    const float* b2       = (const float*)d_in[5];
    const float* bias     = (const float*)d_in[6];
    float* out = (float*)d_out;

    // workspace: H (16384*256 fp32 = 16 MB) then W (4096*4096 fp32 = 64 MB)
    float* H = (float*)d_ws;
    float* W = (float*)((char*)d_ws + (size_t)NUM_CHUNKS * HIDDEN * sizeof(float));

    // Stage 1: H = gelu(codebook @ w1^T + b1)
    hidden_kernel<<<NUM_CHUNKS / 8, 256, 0, stream>>>(codebook, w1, b1, H);

    // Stage 2: W(flat chunks) = H @ w2^T + b2   (M=16384, N=1024, K=256)
    {
        dim3 grid(CHUNK_SIZE / 64, NUM_CHUNKS / 64);
        gemm_abt<<<grid, 256, 0, stream>>>(H, w2, b2, W, NUM_CHUNKS, CHUNK_SIZE, HIDDEN);
    }

    // Stage 3: out = x @ W^T + bias             (M=256, N=4096, K=4096)
    {
        dim3 grid(OUT_F / 64, TOKENS / 64);
        gemm_abt<<<grid, 256, 0, stream>>>(x, W, bias, out, TOKENS, OUT_F, IN_F);
    }
}

// Round 2
// 139.877 us; speedup vs baseline: 2.8238x; 2.8238x over previous
//
#include <hip/hip_runtime.h>
#include <math.h>

#define OUT_F      4096
#define IN_F       4096
#define NUM_CHUNKS 16384
#define CHUNK_SIZE 1024
#define D_ALPHA    64
#define HIDDEN     256
#define TOKENS     256
#define KSPLIT     8

typedef __attribute__((ext_vector_type(8))) __bf16 bf16x8;
typedef __attribute__((ext_vector_type(4))) __bf16 bf16x4;
typedef __attribute__((ext_vector_type(4))) float f32x4;

// async 16B global->LDS (wave-uniform base + lane*16 layout required)
__device__ __forceinline__ void gl2lds16(const void* g, void* l) {
    __builtin_amdgcn_global_load_lds(
        (const __attribute__((address_space(1))) void*)g,
        (__attribute__((address_space(3))) void*)l,
        16, 0, 0);
}

// ---------------- Stage 1: H = gelu(codebook @ w1^T + b1), bf16 out --------
__global__ void hidden_kernel(const float* __restrict__ cb,
                              const float* __restrict__ w1,
                              const float* __restrict__ b1,
                              __bf16* __restrict__ H) {
    const int c0 = blockIdx.x * 8;
    const int t  = threadIdx.x;            // hidden unit 0..255
    __shared__ float sa[8 * 64];
    sa[t]       = cb[(size_t)c0 * 64 + t];
    sa[t + 256] = cb[(size_t)c0 * 64 + t + 256];
    __syncthreads();

    float4 w[16];
    const float4* w1r = reinterpret_cast<const float4*>(w1 + t * 64);
#pragma unroll
    for (int q = 0; q < 16; ++q) w[q] = w1r[q];
    const float b = b1[t];

#pragma unroll
    for (int c = 0; c < 8; ++c) {
        float acc = b;
        const float4* sav = reinterpret_cast<const float4*>(sa + c * 64);
#pragma unroll
        for (int q = 0; q < 16; ++q) {
            float4 a4 = sav[q];
            acc += a4.x * w[q].x + a4.y * w[q].y + a4.z * w[q].z + a4.w * w[q].w;
        }
        float g = 0.5f * acc * (1.0f + erff(acc * 0.70710678118654752f));
        H[(size_t)(c0 + c) * 256 + t] = (__bf16)g;
    }
}

// ---------------- fp32 -> bf16 convert (n divisible by 4) ------------------
__global__ void cvt_bf16(const float* __restrict__ in, __bf16* __restrict__ out,
                         int n4) {
    int i = blockIdx.x * blockDim.x + threadIdx.x;
    if (i < n4) {
        float4 v = reinterpret_cast<const float4*>(in)[i];
        bf16x4 o;
        o.x = (__bf16)v.x; o.y = (__bf16)v.y; o.z = (__bf16)v.z; o.w = (__bf16)v.w;
        reinterpret_cast<bf16x4*>(out)[i] = o;
    }
}

// ---------------- bf16 MFMA GEMM: C = A[M][K] @ B[N][K]^T (+bias) ----------
// 128x128 tile, BK=32, 256 thr = 4 waves (2x2), wave = 64x64 = 4x4 mfma tiles.
// Split-K via blockIdx.z: each z writes its own fp32 partial (ADD_BIAS=false).
template <bool ADD_BIAS, typename OUT_T>
__global__ __launch_bounds__(256) void gemm_bt_mfma(
    const __bf16* __restrict__ A, const __bf16* __restrict__ B,
    const float* __restrict__ bias, OUT_T* __restrict__ C,
    int M, int N, int K, int k_per_split) {
    constexpr int BK = 32;
    __shared__ __bf16 sA[128 * BK];
    __shared__ __bf16 sB[128 * BK];

    const int tid = threadIdx.x;
    const int m0 = blockIdx.y * 128;
    const int n0 = blockIdx.x * 128;
    const int kz0 = blockIdx.z * k_per_split;
    const int kz1 = kz0 + k_per_split;

    // staging: thread t owns 16B chunks at flat element t*8 and 2048 + t*8
    const int srow = tid >> 2;            // t/4   (row 0..63)
    const int scol = (tid & 3) * 8;       // k offset 0/8/16/24
    const __bf16* gA0 = A + (size_t)(m0 + srow) * K + scol;
    const __bf16* gA1 = A + (size_t)(m0 + srow + 64) * K + scol;
    const __bf16* gB0 = B + (size_t)(n0 + srow) * K + scol;
    const __bf16* gB1 = B + (size_t)(n0 + srow + 64) * K + scol;
    __bf16* lA0 = sA + tid * 8;
    __bf16* lA1 = sA + tid * 8 + 2048;
    __bf16* lB0 = sB + tid * 8;
    __bf16* lB1 = sB + tid * 8 + 2048;

    const int wave = tid >> 6;
    const int lane = tid & 63;
    const int wm = (wave & 1) * 64;
    const int wn = (wave >> 1) * 64;
    const int fr = lane & 15;   // free-dim index within 16
    const int fq = lane >> 4;   // quad -> k-group (A/B) / row-group (C)
    const int aoff = (wm + fr) * BK + fq * 8;
    const int boff = (wn + fr) * BK + fq * 8;

    f32x4 acc[4][4] = {};

    for (int k0 = kz0; k0 < kz1; k0 += BK) {
        gl2lds16(gA0 + k0, lA0);
        gl2lds16(gA1 + k0, lA1);
        gl2lds16(gB0 + k0, lB0);
        gl2lds16(gB1 + k0, lB1);
        __syncthreads();   // drains vmcnt -> LDS writes visible

        bf16x8 af[4], bfr[4];
#pragma unroll
        for (int i = 0; i < 4; ++i) {
            af[i]  = *reinterpret_cast<const bf16x8*>(sA + aoff + i * 16 * BK);
            bfr[i] = *reinterpret_cast<const bf16x8*>(sB + boff + i * 16 * BK);
        }
#pragma unroll
        for (int i = 0; i < 4; ++i)
#pragma unroll
            for (int j = 0; j < 4; ++j)
                acc[i][j] = __builtin_amdgcn_mfma_f32_16x16x32_bf16(
                    af[i], bfr[j], acc[i][j], 0, 0, 0);
        __syncthreads();   // before next overwrite
    }

    // epilogue: D lane mapping col = lane&15, row = fq*4 + reg
    const size_t zoff = ADD_BIAS ? 0 : (size_t)blockIdx.z * (size_t)M * N;
#pragma unroll
    for (int j = 0; j < 4; ++j) {
        const int col = n0 + wn + j * 16 + fr;
        const float bv = ADD_BIAS ? bias[col] : 0.0f;
#pragma unroll
        for (int i = 0; i < 4; ++i) {
            const int rbase = m0 + wm + i * 16 + fq * 4;
#pragma unroll
            for (int r = 0; r < 4; ++r) {
                float v = acc[i][j][r] + bv;
                C[zoff + (size_t)(rbase + r) * N + col] = (OUT_T)v;
            }
        }
    }
}

// ---------------- reduce split-K partials + bias -> out --------------------
__global__ void reduce_out(const float* __restrict__ part,
                           const float* __restrict__ bias,
                           float* __restrict__ out) {
    const int i = blockIdx.x * blockDim.x + threadIdx.x;   // float4 index
    const int n4 = TOKENS * OUT_F / 4;                     // 262144
    if (i >= n4) return;
    const float4 b4 = reinterpret_cast<const float4*>(bias)[i & (OUT_F / 4 - 1)];
    float4 s = b4;
#pragma unroll
    for (int z = 0; z < KSPLIT; ++z) {
        float4 p = reinterpret_cast<const float4*>(part + (size_t)z * TOKENS * OUT_F)[i];
        s.x += p.x; s.y += p.y; s.z += p.z; s.w += p.w;
    }
    reinterpret_cast<float4*>(out)[i] = s;
}

extern "C" void kernel_launch(void* const* d_in, const int* in_sizes, int n_in,
                              void* d_out, int out_size, void* d_ws, size_t ws_size,
                              hipStream_t stream) {
    const float* x        = (const float*)d_in[0];
    const float* codebook = (const float*)d_in[1];
    const float* w1       = (const float*)d_in[2];
    const float* b1       = (const float*)d_in[3];
    const float* w2       = (const float*)d_in[4];
    const float* b2       = (const float*)d_in[5];
    const float* bias     = (const float*)d_in[6];
    float* out = (float*)d_out;

    // ws layout (bytes):
    //   H_bf16   @ 0        8 MB  (16384 x 256)
    //   W_bf16   @ 8  MB   32 MB  (4096 x 4096)
    //   x_bf16   @ 40 MB    2 MB  (256 x 4096)
    //   w2_bf16  @ 42 MB  0.5 MB  (1024 x 256)
    //   partials @ 43 MB   32 MB  (KSPLIT x 256 x 4096 fp32)
    char* ws = (char*)d_ws;
    __bf16* H   = (__bf16*)(ws);
    __bf16* W   = (__bf16*)(ws + (8u << 20));
    __bf16* xb  = (__bf16*)(ws + (40u << 20));
    __bf16* w2b = (__bf16*)(ws + (42u << 20));
    float*  prt = (float*)(ws + (43u << 20));

    // converts
    cvt_bf16<<<(TOKENS * IN_F / 4 + 255) / 256, 256, 0, stream>>>(x, xb, TOKENS * IN_F / 4);
    cvt_bf16<<<(CHUNK_SIZE * HIDDEN / 4 + 255) / 256, 256, 0, stream>>>(w2, w2b, CHUNK_SIZE * HIDDEN / 4);

    // Stage 1: H = gelu(codebook @ w1^T + b1)
    hidden_kernel<<<NUM_CHUNKS / 8, 256, 0, stream>>>(codebook, w1, b1, H);

    // Stage 2: W = H @ w2^T + b2   (M=16384, N=1024, K=256), bf16 out
    {
        dim3 grid(CHUNK_SIZE / 128, NUM_CHUNKS / 128, 1);
        gemm_bt_mfma<true, __bf16><<<grid, 256, 0, stream>>>(
            H, w2b, b2, W, NUM_CHUNKS, CHUNK_SIZE, HIDDEN, HIDDEN);
    }

    // Stage 3: partials[z] = x @ W^T over k-slice   (M=256, N=4096, K=4096)
    {
        dim3 grid(OUT_F / 128, TOKENS / 128, KSPLIT);
        gemm_bt_mfma<false, float><<<grid, 256, 0, stream>>>(
            xb, W, nullptr, prt, TOKENS, OUT_F, IN_F, IN_F / KSPLIT);
    }

    // reduce partials + bias -> out
    reduce_out<<<(TOKENS * OUT_F / 4 + 255) / 256, 256, 0, stream>>>(prt, bias, out);
}

// Round 3
// 119.634 us; speedup vs baseline: 3.3016x; 1.1692x over previous
//
#include <hip/hip_runtime.h>
#include <math.h>

#define OUT_F      4096
#define IN_F       4096
#define NUM_CHUNKS 16384
#define CHUNK_SIZE 1024
#define D_ALPHA    64
#define HIDDEN     256
#define TOKENS     256
#define ZY         4     // split-K for Y gemm
#define ZO         4     // split-K for out gemm

typedef __attribute__((ext_vector_type(8))) __bf16 bf16x8;
typedef __attribute__((ext_vector_type(4))) __bf16 bf16x4;
typedef __attribute__((ext_vector_type(4))) float f32x4;

__device__ __forceinline__ void gl2lds16(const void* g, void* l) {
    __builtin_amdgcn_global_load_lds(
        (const __attribute__((address_space(1))) void*)g,
        (__attribute__((address_space(3))) void*)l,
        16, 0, 0);
}

// ---- x fp32 -> bf16, fused per-token dot with tiled b2: xb2[t] -------------
__global__ __launch_bounds__(256) void cvt_x_rowdot(
    const float* __restrict__ x, const float* __restrict__ b2,
    __bf16* __restrict__ xb, float* __restrict__ xb2) {
    const int t   = blockIdx.x;          // token row
    const int tid = threadIdx.x;
    const float4* xr  = reinterpret_cast<const float4*>(x + (size_t)t * IN_F);
    const float4* b24 = reinterpret_cast<const float4*>(b2);
    bf16x4* xb4 = reinterpret_cast<bf16x4*>(xb + (size_t)t * IN_F);
    float acc = 0.0f;
#pragma unroll
    for (int ii = 0; ii < 4; ++ii) {
        const int idx = ii * 256 + tid;
        float4 v = xr[idx];
        bf16x4 o;
        o.x = (__bf16)v.x; o.y = (__bf16)v.y; o.z = (__bf16)v.z; o.w = (__bf16)v.w;
        xb4[idx] = o;
        float4 b = b24[idx & 255];
        acc += v.x * b.x + v.y * b.y + v.z * b.z + v.w * b.w;
    }
#pragma unroll
    for (int off = 32; off > 0; off >>= 1) acc += __shfl_down(acc, off, 64);
    __shared__ float ws_[4];
    if ((tid & 63) == 0) ws_[tid >> 6] = acc;
    __syncthreads();
    if (tid == 0) xb2[t] = ws_[0] + ws_[1] + ws_[2] + ws_[3];
}

// ---- w2 (1024p x 256h) fp32 -> w2t bf16 (256h x 1024p), tiled transpose ----
__global__ __launch_bounds__(256) void cvt_w2t(
    const float* __restrict__ w2, __bf16* __restrict__ w2t) {
    __shared__ float tile[32][33];
    const int h0 = blockIdx.x * 32;
    const int p0 = blockIdx.y * 32;
    const int r = threadIdx.x >> 5;
    const int c = threadIdx.x & 31;
#pragma unroll
    for (int ii = 0; ii < 4; ++ii)
        tile[r + 8 * ii][c] = w2[(size_t)(p0 + r + 8 * ii) * HIDDEN + h0 + c];
    __syncthreads();
#pragma unroll
    for (int ii = 0; ii < 4; ++ii)
        w2t[(size_t)(h0 + r + 8 * ii) * CHUNK_SIZE + p0 + c] =
            (__bf16)tile[c][r + 8 * ii];
}

// ---- Stage 1: H = gelu(codebook @ w1^T + b1), bf16 out ---------------------
__global__ __launch_bounds__(256) void hidden_kernel(
    const float* __restrict__ cb, const float* __restrict__ w1,
    const float* __restrict__ b1, __bf16* __restrict__ H) {
    const int c0 = blockIdx.x * 8;
    const int t  = threadIdx.x;
    __shared__ float sa[8 * 64];
    sa[t]       = cb[(size_t)c0 * 64 + t];
    sa[t + 256] = cb[(size_t)c0 * 64 + t + 256];
    __syncthreads();

    float4 w[16];
    const float4* w1r = reinterpret_cast<const float4*>(w1 + t * 64);
#pragma unroll
    for (int q = 0; q < 16; ++q) w[q] = w1r[q];
    const float b = b1[t];

#pragma unroll
    for (int c = 0; c < 8; ++c) {
        float acc = b;
        const float4* sav = reinterpret_cast<const float4*>(sa + c * 64);
#pragma unroll
        for (int q = 0; q < 16; ++q) {
            float4 a4 = sav[q];
            acc += a4.x * w[q].x + a4.y * w[q].y + a4.z * w[q].z + a4.w * w[q].w;
        }
        float g = 0.5f * acc * (1.0f + erff(acc * 0.70710678118654752f));
        H[(size_t)(c0 + c) * 256 + t] = (__bf16)g;
    }
}

// ---- bf16 MFMA GEMM: part[z] = A[M][K] @ B[N][K]^T over k-slice ------------
// 128x128 tile, BK=32, 256 thr = 4 waves (2x2), wave = 64x64 = 4x4 mfma.
__global__ __launch_bounds__(256) void gemm_bt_mfma(
    const __bf16* __restrict__ A, const __bf16* __restrict__ B,
    float* __restrict__ C, int M, int N, int K, int k_per_split) {
    constexpr int BK = 32;
    __shared__ __bf16 sA[128 * BK];
    __shared__ __bf16 sB[128 * BK];

    const int tid = threadIdx.x;
    const int m0 = blockIdx.y * 128;
    const int n0 = blockIdx.x * 128;
    const int kz0 = blockIdx.z * k_per_split;
    const int kz1 = kz0 + k_per_split;

    const int srow = tid >> 2;
    const int scol = (tid & 3) * 8;
    const __bf16* gA0 = A + (size_t)(m0 + srow) * K + scol;
    const __bf16* gA1 = A + (size_t)(m0 + srow + 64) * K + scol;
    const __bf16* gB0 = B + (size_t)(n0 + srow) * K + scol;
    const __bf16* gB1 = B + (size_t)(n0 + srow + 64) * K + scol;
    __bf16* lA0 = sA + tid * 8;
    __bf16* lA1 = sA + tid * 8 + 2048;
    __bf16* lB0 = sB + tid * 8;
    __bf16* lB1 = sB + tid * 8 + 2048;

    const int wave = tid >> 6;
    const int lane = tid & 63;
    const int wm = (wave & 1) * 64;
    const int wn = (wave >> 1) * 64;
    const int fr = lane & 15;
    const int fq = lane >> 4;
    const int aoff = (wm + fr) * BK + fq * 8;
    const int boff = (wn + fr) * BK + fq * 8;

    f32x4 acc[4][4] = {};

    for (int k0 = kz0; k0 < kz1; k0 += BK) {
        gl2lds16(gA0 + k0, lA0);
        gl2lds16(gA1 + k0, lA1);
        gl2lds16(gB0 + k0, lB0);
        gl2lds16(gB1 + k0, lB1);
        __syncthreads();

        bf16x8 af[4], bfr[4];
#pragma unroll
        for (int i = 0; i < 4; ++i) {
            af[i]  = *reinterpret_cast<const bf16x8*>(sA + aoff + i * 16 * BK);
            bfr[i] = *reinterpret_cast<const bf16x8*>(sB + boff + i * 16 * BK);
        }
#pragma unroll
        for (int i = 0; i < 4; ++i)
#pragma unroll
            for (int j = 0; j < 4; ++j)
                acc[i][j] = __builtin_amdgcn_mfma_f32_16x16x32_bf16(
                    af[i], bfr[j], acc[i][j], 0, 0, 0);
        __syncthreads();
    }

    const size_t zoff = (size_t)blockIdx.z * (size_t)M * N;
#pragma unroll
    for (int j = 0; j < 4; ++j) {
        const int col = n0 + wn + j * 16 + fr;
#pragma unroll
        for (int i = 0; i < 4; ++i) {
            const int rbase = m0 + wm + i * 16 + fq * 4;
#pragma unroll
            for (int r = 0; r < 4; ++r)
                C[zoff + (size_t)(rbase + r) * N + col] = acc[i][j][r];
        }
    }
}

// ---- reduce Y partials -> bf16 Y -------------------------------------------
__global__ __launch_bounds__(256) void reduce_y(
    const float* __restrict__ part, __bf16* __restrict__ Y) {
    const int i = blockIdx.x * blockDim.x + threadIdx.x;   // float4 idx
    const int n4 = 1024 * HIDDEN / 4;
    if (i >= n4) return;
    float4 s = {0, 0, 0, 0};
#pragma unroll
    for (int z = 0; z < ZY; ++z) {
        float4 p = reinterpret_cast<const float4*>(part + (size_t)z * 1024 * HIDDEN)[i];
        s.x += p.x; s.y += p.y; s.z += p.z; s.w += p.w;
    }
    bf16x4 o;
    o.x = (__bf16)s.x; o.y = (__bf16)s.y; o.z = (__bf16)s.z; o.w = (__bf16)s.w;
    reinterpret_cast<bf16x4*>(Y)[i] = o;
}

// ---- reduce out partials + bias[col] + xb2[row] -> out ---------------------
__global__ __launch_bounds__(256) void reduce_out(
    const float* __restrict__ part, const float* __restrict__ bias,
    const float* __restrict__ xb2, float* __restrict__ out) {
    const int i = blockIdx.x * blockDim.x + threadIdx.x;   // float4 idx
    const int n4 = TOKENS * OUT_F / 4;
    if (i >= n4) return;
    const int t = i >> 10;                                  // 1024 f4 per row
    const float rs = xb2[t];
    float4 s = reinterpret_cast<const float4*>(bias)[i & 1023];
    s.x += rs; s.y += rs; s.z += rs; s.w += rs;
#pragma unroll
    for (int z = 0; z < ZO; ++z) {
        float4 p = reinterpret_cast<const float4*>(part + (size_t)z * TOKENS * OUT_F)[i];
        s.x += p.x; s.y += p.y; s.z += p.z; s.w += p.w;
    }
    reinterpret_cast<float4*>(out)[i] = s;
}

extern "C" void kernel_launch(void* const* d_in, const int* in_sizes, int n_in,
                              void* d_out, int out_size, void* d_ws, size_t ws_size,
                              hipStream_t stream) {
    const float* x        = (const float*)d_in[0];
    const float* codebook = (const float*)d_in[1];
    const float* w1       = (const float*)d_in[2];
    const float* b1       = (const float*)d_in[3];
    const float* w2       = (const float*)d_in[4];
    const float* b2       = (const float*)d_in[5];
    const float* bias     = (const float*)d_in[6];
    float* out = (float*)d_out;

    // ws layout (MB offsets):
    //   xb   bf16 256x4096   2 MB @ 0
    //   w2t  bf16 256x1024  .5 MB @ 2
    //   H    bf16 16384x256  8 MB @ 3
    //   Y    bf16 1024x256  .5 MB @ 11
    //   xb2  fp32 256        1 KB @ 12
    //   Yp   fp32 ZY x 1024x256   4 MB @ 13
    //   outp fp32 ZO x 256x4096  16 MB @ 17
    char* ws = (char*)d_ws;
    __bf16* xb  = (__bf16*)(ws);
    __bf16* w2t = (__bf16*)(ws + (2u << 20));
    __bf16* H   = (__bf16*)(ws + (3u << 20));
    __bf16* Y   = (__bf16*)(ws + (11u << 20));
    float*  xb2 = (float*)(ws + (12u << 20));
    float*  Yp  = (float*)(ws + (13u << 20));
    float*  outp= (float*)(ws + (17u << 20));

    // independent prep kernels
    cvt_x_rowdot<<<TOKENS, 256, 0, stream>>>(x, b2, xb, xb2);
    {
        dim3 grid(HIDDEN / 32, CHUNK_SIZE / 32);
        cvt_w2t<<<grid, 256, 0, stream>>>(w2, w2t);
    }
    hidden_kernel<<<NUM_CHUNKS / 8, 256, 0, stream>>>(codebook, w1, b1, H);

    // Y partials = xr(1024x1024) @ w2t(256x1024)^T  (M=1024,N=256,K=1024)
    {
        dim3 grid(HIDDEN / 128, 1024 / 128, ZY);
        gemm_bt_mfma<<<grid, 256, 0, stream>>>(xb, w2t, Yp, 1024, HIDDEN, 1024, 1024 / ZY);
    }
    reduce_y<<<(1024 * HIDDEN / 4) / 256, 256, 0, stream>>>(Yp, Y);

    // out partials = Ycat(256x1024) @ Hflat(4096x1024)^T (M=256,N=4096,K=1024)
    {
        dim3 grid(OUT_F / 128, TOKENS / 128, ZO);
        gemm_bt_mfma<<<grid, 256, 0, stream>>>(Y, H, outp, TOKENS, OUT_F, 1024, 1024 / ZO);
    }
    reduce_out<<<(TOKENS * OUT_F / 4) / 256, 256, 0, stream>>>(outp, bias, xb2, out);
}